// Round 3
// baseline (570.360 us; speedup 1.0000x reference)
//
#include <hip/hip_runtime.h>

// ---------- bf16 helpers (raw ushort bit ops, RNE store) ----------
__device__ __forceinline__ float bf2f(unsigned short u) {
  union { unsigned int i; float f; } c; c.i = ((unsigned int)u) << 16; return c.f;
}
__device__ __forceinline__ unsigned short f2bf(float f) {
  union { float f; unsigned int i; } c; c.f = f;
  unsigned int x = c.i;
  return (unsigned short)((x + 0x7fffu + ((x >> 16) & 1u)) >> 16);
}

#define DD 128
#define HH 64
#define CC 40

// ---------- dtype detect ----------
// flags[0] = edges are int64 (odd int32 words all zero over first 4096 elems)
// flags[1] = x is fp32 (low ushort of each word does NOT look like a bf16 of N(0,1))
__global__ void detect(const unsigned int* e32, const unsigned int* x32, int* flags) {
  __shared__ unsigned int redOr[256];
  __shared__ int redCnt[256];
  int tid = threadIdx.x;
  unsigned int v = 0;
  for (int i = tid; i < 4096; i += 256) v |= e32[2 * i + 1];
  int cnt = 0;
  for (int i = tid; i < 4096; i += 256) {
    unsigned int w = x32[i];
    unsigned int expo = (w >> 7) & 0xffu;          // low-ushort bf16 exponent field
    unsigned short lo = (unsigned short)(w & 0xffffu);
    if (lo == 0 || (expo >= 100u && expo <= 133u)) cnt++;
  }
  redOr[tid] = v; redCnt[tid] = cnt; __syncthreads();
  for (int s = 128; s > 0; s >>= 1) {
    if (tid < s) { redOr[tid] |= redOr[tid + s]; redCnt[tid] += redCnt[tid + s]; }
    __syncthreads();
  }
  if (tid == 0) {
    flags[0] = (redOr[0] == 0u) ? 1 : 0;
    flags[1] = (redCnt[0] < 2048) ? 1 : 0;
  }
}

__global__ void convert_edges(const int* e32, int E, int N, const int* flags,
                              int* src, int* dst) {
  int i = blockIdx.x * blockDim.x + threadIdx.x;
  if (i >= E) return;
  int s, d;
  if (flags[0]) { s = e32[2 * i]; d = e32[2 * (E + i)]; }
  else          { s = e32[i];     d = e32[E + i]; }
  src[i] = min(max(s, 0), N - 1);
  dst[i] = min(max(d, 0), N - 1);
}

__global__ void count_deg(const int* dst, int E, int* deg) {
  int i = blockIdx.x * blockDim.x + threadIdx.x;
  if (i < E) atomicAdd(&deg[dst[i]], 1);
}

// ---------- exclusive scan over deg (1024 elems / block) ----------
__global__ void scan_phase1(const int* deg, int n, int* bsums) {
  __shared__ int red[256];
  int tid = threadIdx.x;
  int base = blockIdx.x * 1024 + tid * 4;
  int s = 0;
  for (int k = 0; k < 4; k++) { int i = base + k; if (i < n) s += deg[i]; }
  red[tid] = s; __syncthreads();
  for (int st = 128; st > 0; st >>= 1) {
    if (tid < st) red[tid] += red[tid + st];
    __syncthreads();
  }
  if (tid == 0) bsums[blockIdx.x] = red[0];
}

__global__ void scan_phase2(int* bsums, int nb, int* row_ptr, int n) {
  __shared__ int tmp[1024];
  int tid = threadIdx.x;
  int v = (tid < nb) ? bsums[tid] : 0;
  tmp[tid] = v; __syncthreads();
  for (int st = 1; st < 1024; st <<= 1) {
    int t = (tid >= st) ? tmp[tid - st] : 0;
    __syncthreads();
    tmp[tid] += t;
    __syncthreads();
  }
  if (tid < nb) bsums[tid] = tmp[tid] - v;      // exclusive block offsets
  if (tid == nb - 1) row_ptr[n] = tmp[tid];     // total (= E)
}

__global__ void scan_phase3(const int* deg, int n, const int* boff,
                            int* row_ptr, int* fill, float* invd) {
  __shared__ int red[256];
  int tid = threadIdx.x;
  int base = blockIdx.x * 1024 + tid * 4;
  int d[4]; int s = 0;
  for (int k = 0; k < 4; k++) { int i = base + k; d[k] = (i < n) ? deg[i] : 0; s += d[k]; }
  red[tid] = s; __syncthreads();
  for (int st = 1; st < 256; st <<= 1) {
    int t = (tid >= st) ? red[tid - st] : 0;
    __syncthreads();
    red[tid] += t;
    __syncthreads();
  }
  int run = boff[blockIdx.x] + red[tid] - s;    // exclusive prefix for this thread
  for (int k = 0; k < 4; k++) {
    int i = base + k;
    if (i < n) {
      row_ptr[i] = run; fill[i] = run;
      invd[i] = 1.0f / (float)max(d[k], 1);
      run += d[k];
    }
  }
}

__global__ void fill_csr(const int* src, const int* dst, int E, int* fill, int* col) {
  int i = blockIdx.x * blockDim.x + threadIdx.x;
  if (i < E) {
    int p = atomicAdd(&fill[dst[i]], 1);
    col[p] = src[i];
  }
}

// ---------- pack weights to fp32, lane-coalesced pair layout ----------
// Wp1f[p*64+j] = {W1l[2p][j], W1l[2p+1][j], W1r[2p][j], W1r[2p+1][j]}
// Wp2f[p*40+c] = {W2c[2p][c], W2c[2p+1][c]}, W2c[k<64]=W2l[k][c], else W2r[k-64][c]
__global__ void prep_w(const void* W1l, const void* W1r, const void* b1,
                       const void* W2l, const void* W2r, const void* b2,
                       const int* flags, float4* Wp1f, float2* Wp2f,
                       float* b1f, float* b2f) {
  int tid = threadIdx.x;
  int isf = flags[1];
  auto rd = [&](const void* p, int i) -> float {
    return isf ? ((const float*)p)[i] : bf2f(((const unsigned short*)p)[i]);
  };
  for (int idx = tid; idx < 64 * 64; idx += 256) {
    int p = idx >> 6, j = idx & 63;
    Wp1f[idx] = make_float4(rd(W1l, (2 * p) * HH + j), rd(W1l, (2 * p + 1) * HH + j),
                            rd(W1r, (2 * p) * HH + j), rd(W1r, (2 * p + 1) * HH + j));
  }
  for (int idx = tid; idx < 64 * CC; idx += 256) {
    int p = idx / CC, c = idx % CC;
    int k0 = 2 * p, k1 = 2 * p + 1;
    float a  = (k0 < HH) ? rd(W2l, k0 * CC + c) : rd(W2r, (k0 - HH) * CC + c);
    float bb = (k1 < HH) ? rd(W2l, k1 * CC + c) : rd(W2r, (k1 - HH) * CC + c);
    Wp2f[idx] = make_float2(a, bb);
  }
  if (tid < HH) b1f[tid] = rd(b1, tid);
  if (tid < CC) b2f[tid] = rd(b2, tid);
}

// ---------- transform1: t1 = x@W1_l (bf16), s1 = x@W1_r + b1 (bf16) ----------
// block=256 (4 waves), each wave owns 8 nodes; lane j owns output column j.
__global__ __launch_bounds__(256) void transform1(const void* xraw, const int* flags,
                                                  const float4* Wp1f, const float* b1f,
                                                  unsigned short* t1, unsigned short* s1,
                                                  int N) {
  __shared__ float vx[32 * DD];            // 16 KB: 32 nodes x 128 floats
  int wave = threadIdx.x >> 6, lane = threadIdx.x & 63;
  int nodeBase = blockIdx.x * 32 + wave * 8;
  float* myv = &vx[wave * 8 * DD];

  if (flags[1]) {                                        // fp32 input
    const float2* x2 = (const float2*)xraw;
    for (int k = 0; k < 8; k++) {
      int n = nodeBase + k;
      if (n < N) {
        float2 t = x2[(size_t)n * 64 + lane];
        *(float2*)&myv[k * DD + 2 * lane] = t;
      }
    }
  } else {                                               // bf16 input
    const unsigned int* x32 = (const unsigned int*)xraw;
    for (int k = 0; k < 8; k++) {
      int n = nodeBase + k;
      if (n < N) {
        unsigned int w = x32[(size_t)n * 64 + lane];
        float2 t = make_float2(bf2f((unsigned short)(w & 0xffffu)),
                               bf2f((unsigned short)(w >> 16)));
        *(float2*)&myv[k * DD + 2 * lane] = t;
      }
    }
  }
  __syncthreads();   // fence: LDS staging visible (+ compiler ordering barrier)

  float acct[8] = {0, 0, 0, 0, 0, 0, 0, 0};
  float accs[8] = {0, 0, 0, 0, 0, 0, 0, 0};
  const float2* v2 = (const float2*)myv;
  int j = lane;
  for (int p = 0; p < 64; p++) {
    float4 w = Wp1f[p * 64 + j];
#pragma unroll
    for (int k = 0; k < 8; k++) {
      float2 vv = v2[k * 64 + p];                // broadcast LDS read
      acct[k] += vv.x * w.x + vv.y * w.y;
      accs[k] += vv.x * w.z + vv.y * w.w;
    }
  }
  float bb = b1f[j];
  for (int k = 0; k < 8; k++) {
    int n = nodeBase + k;
    if (n < N) {
      t1[n * HH + j] = f2bf(acct[k]);
      s1[n * HH + j] = f2bf(accs[k] + bb);
    }
  }
}

// ---------- aggregate1: h = relu(mean(t1[nbrs]) + s1) ----------
// one wave per node; lane = feature
__global__ __launch_bounds__(256) void aggregate1(const unsigned short* t1,
                                                  const unsigned short* s1,
                                                  const int* row_ptr, const float* invd,
                                                  const int* col, unsigned short* h, int N) {
  int wave = threadIdx.x >> 6, lane = threadIdx.x & 63;
  int n = blockIdx.x * 4 + wave;
  if (n >= N) return;
  int start = row_ptr[n], end = row_ptr[n + 1];
  float acc = 0.f;
  for (int base = start; base < end; base += 64) {
    int cnt = min(64, end - base);
    int idx = (base + lane < end) ? col[base + lane] : 0;
    int i = 0;
    for (; i + 4 <= cnt; i += 4) {
      int s0 = __shfl(idx, i, 64), s1_ = __shfl(idx, i + 1, 64);
      int s2 = __shfl(idx, i + 2, 64), s3 = __shfl(idx, i + 3, 64);
      float a0 = bf2f(t1[s0 * HH + lane]);
      float a1 = bf2f(t1[s1_ * HH + lane]);
      float a2 = bf2f(t1[s2 * HH + lane]);
      float a3 = bf2f(t1[s3 * HH + lane]);
      acc += (a0 + a1) + (a2 + a3);
    }
    for (; i < cnt; i++) {
      int s = __shfl(idx, i, 64);
      acc += bf2f(t1[s * HH + lane]);
    }
  }
  float r = acc * invd[n] + bf2f(s1[n * HH + lane]);
  h[n * HH + lane] = f2bf(fmaxf(r, 0.f));
}

// ---------- layer2 fused: aggh = mean(h[nbrs]); logits = [aggh|h]@W2c + b2; log_softmax ----------
// block=256 (4 waves); each wave owns 4 nodes; lane c (<40) owns output class c.
// OUTPUT IS FP32 (reference returns float32; harness reads d_out as float*).
__global__ __launch_bounds__(256) void layer2(const unsigned short* h,
                                              const int* row_ptr, const float* invd,
                                              const int* col, const float2* Wp2f,
                                              const float* b2f,
                                              float* out, int N) {
  __shared__ float v[16 * DD];             // 8 KB: 16 nodes x 128 floats
  int wave = threadIdx.x >> 6, lane = threadIdx.x & 63;
  int nodeBase = blockIdx.x * 16 + wave * 4;
  float* myv = &v[wave * 4 * DD];

  for (int k = 0; k < 4; k++) {
    int n = nodeBase + k;
    if (n >= N) continue;
    int start = row_ptr[n], end = row_ptr[n + 1];
    float acc = 0.f;
    for (int base = start; base < end; base += 64) {
      int cnt = min(64, end - base);
      int idx = (base + lane < end) ? col[base + lane] : 0;
      int i = 0;
      for (; i + 4 <= cnt; i += 4) {
        int s0 = __shfl(idx, i, 64), s1_ = __shfl(idx, i + 1, 64);
        int s2 = __shfl(idx, i + 2, 64), s3 = __shfl(idx, i + 3, 64);
        float a0 = bf2f(h[s0 * HH + lane]);
        float a1 = bf2f(h[s1_ * HH + lane]);
        float a2 = bf2f(h[s2 * HH + lane]);
        float a3 = bf2f(h[s3 * HH + lane]);
        acc += (a0 + a1) + (a2 + a3);
      }
      for (; i < cnt; i++) {
        int s = __shfl(idx, i, 64);
        acc += bf2f(h[s * HH + lane]);
      }
    }
    myv[k * DD + lane]      = acc * invd[n];          // aggh features [0..63]
    myv[k * DD + 64 + lane] = bf2f(h[n * HH + lane]); // self features [64..127]
  }
  __syncthreads();   // fence: LDS staging visible (+ compiler ordering barrier)

  float accc[4] = {0, 0, 0, 0};
  if (lane < CC) {
    const float2* v2 = (const float2*)myv;
    for (int p = 0; p < 64; p++) {
      float2 w = Wp2f[p * CC + lane];
#pragma unroll
      for (int k = 0; k < 4; k++) {
        float2 vv = v2[k * 64 + p];                   // broadcast LDS read
        accc[k] += vv.x * w.x + vv.y * w.y;
      }
    }
    float bb = b2f[lane];
    for (int k = 0; k < 4; k++) accc[k] += bb;
  }

  for (int k = 0; k < 4; k++) {
    int n = nodeBase + k;
    float val = (lane < CC) ? accc[k] : -INFINITY;
    float m = val;
    for (int off = 32; off > 0; off >>= 1) m = fmaxf(m, __shfl_xor(m, off, 64));
    float e = (lane < CC) ? __expf(val - m) : 0.f;
    float ssum = e;
    for (int off = 32; off > 0; off >>= 1) ssum += __shfl_xor(ssum, off, 64);
    if (lane < CC && n < N) {
      out[n * CC + lane] = val - m - __logf(ssum);    // fp32 store
    }
  }
}

extern "C" void kernel_launch(void* const* d_in, const int* in_sizes, int n_in,
                              void* d_out, int out_size, void* d_ws, size_t ws_size,
                              hipStream_t stream) {
  const void* x   = d_in[0];
  const int*  e   = (const int*)d_in[1];
  const void* W1l = d_in[2];
  const void* W1r = d_in[3];
  const void* b1  = d_in[4];
  const void* W2l = d_in[5];
  const void* W2r = d_in[6];
  const void* b2  = d_in[7];
  float* out = (float*)d_out;

  const int N = in_sizes[0] / DD;       // 100000
  const int E = in_sizes[1] / 2;        // 1600000
  const int NB = (N + 1023) / 1024;     // scan blocks (98)

  char* w = (char*)d_ws;
  size_t off = 0;
  auto carve = [&](size_t bytes) -> void* {
    void* p = (void*)(w + off);
    off += (bytes + 255) & ~(size_t)255;
    return p;
  };
  int* src     = (int*)carve((size_t)E * 4);
  int* dst     = (int*)carve((size_t)E * 4);
  int* col     = (int*)carve((size_t)E * 4);
  int* deg     = (int*)carve((size_t)N * 4);
  int* row_ptr = (int*)carve((size_t)(N + 1) * 4);
  int* fill    = (int*)carve((size_t)N * 4);
  float* invd  = (float*)carve((size_t)N * 4);
  int* bsums   = (int*)carve((size_t)NB * 4);
  int* flags   = (int*)carve(8);
  unsigned short* t1  = (unsigned short*)carve((size_t)N * HH * 2);
  unsigned short* s1  = (unsigned short*)carve((size_t)N * HH * 2);
  unsigned short* h   = (unsigned short*)carve((size_t)N * HH * 2);
  float4* Wp1f = (float4*)carve(64 * 64 * sizeof(float4));
  float2* Wp2f = (float2*)carve(64 * CC * sizeof(float2));
  float* b1f   = (float*)carve(HH * sizeof(float));
  float* b2f   = (float*)carve(CC * sizeof(float));
  (void)ws_size; (void)n_in; (void)out_size;

  hipMemsetAsync(deg, 0, (size_t)N * 4, stream);
  detect<<<1, 256, 0, stream>>>((const unsigned int*)e, (const unsigned int*)x, flags);
  convert_edges<<<(E + 255) / 256, 256, 0, stream>>>(e, E, N, flags, src, dst);
  count_deg<<<(E + 255) / 256, 256, 0, stream>>>(dst, E, deg);
  scan_phase1<<<NB, 256, 0, stream>>>(deg, N, bsums);
  scan_phase2<<<1, 1024, 0, stream>>>(bsums, NB, row_ptr, N);
  scan_phase3<<<NB, 256, 0, stream>>>(deg, N, bsums, row_ptr, fill, invd);
  fill_csr<<<(E + 255) / 256, 256, 0, stream>>>(src, dst, E, fill, col);
  prep_w<<<1, 256, 0, stream>>>(W1l, W1r, b1, W2l, W2r, b2, flags, Wp1f, Wp2f, b1f, b2f);
  transform1<<<(N + 31) / 32, 256, 0, stream>>>(x, flags, Wp1f, b1f, t1, s1, N);
  aggregate1<<<(N + 3) / 4, 256, 0, stream>>>(t1, s1, row_ptr, invd, col, h, N);
  layer2<<<(N + 15) / 16, 256, 0, stream>>>(h, row_ptr, invd, col, Wp2f, b2f, out, N);
}

// Round 4
// 544.871 us; speedup vs baseline: 1.0468x; 1.0468x over previous
//
#include <hip/hip_runtime.h>

// ---------- bf16 helpers (raw ushort bit ops, RNE store) ----------
__device__ __forceinline__ float bf2f(unsigned short u) {
  union { unsigned int i; float f; } c; c.i = ((unsigned int)u) << 16; return c.f;
}
__device__ __forceinline__ unsigned short f2bf(float f) {
  union { float f; unsigned int i; } c; c.f = f;
  unsigned int x = c.i;
  return (unsigned short)((x + 0x7fffu + ((x >> 16) & 1u)) >> 16);
}
__device__ __forceinline__ float lo16(unsigned int w) { return bf2f((unsigned short)(w & 0xffffu)); }
__device__ __forceinline__ float hi16(unsigned int w) { return bf2f((unsigned short)(w >> 16)); }

#define DD 128
#define HH 64
#define CC 40

// ---------- dtype detect ----------
// flags[0] = edges are int64 (odd int32 words all zero over first 4096 elems)
// flags[1] = x is fp32 (low ushort of each word does NOT look like a bf16 of N(0,1))
__global__ void detect(const unsigned int* e32, const unsigned int* x32, int* flags) {
  __shared__ unsigned int redOr[256];
  __shared__ int redCnt[256];
  int tid = threadIdx.x;
  unsigned int v = 0;
  for (int i = tid; i < 4096; i += 256) v |= e32[2 * i + 1];
  int cnt = 0;
  for (int i = tid; i < 4096; i += 256) {
    unsigned int w = x32[i];
    unsigned int expo = (w >> 7) & 0xffu;          // low-ushort bf16 exponent field
    unsigned short lo = (unsigned short)(w & 0xffffu);
    if (lo == 0 || (expo >= 100u && expo <= 133u)) cnt++;
  }
  redOr[tid] = v; redCnt[tid] = cnt; __syncthreads();
  for (int s = 128; s > 0; s >>= 1) {
    if (tid < s) { redOr[tid] |= redOr[tid + s]; redCnt[tid] += redCnt[tid + s]; }
    __syncthreads();
  }
  if (tid == 0) {
    flags[0] = (redOr[0] == 0u) ? 1 : 0;
    flags[1] = (redCnt[0] < 2048) ? 1 : 0;
  }
}

// ---------- CSR build (edge decode inlined; no materialized src/dst) ----------
__global__ void count_deg(const int* e32, int E, int N, const int* flags, int* deg) {
  int i = blockIdx.x * blockDim.x + threadIdx.x;
  if (i >= E) return;
  int d = flags[0] ? e32[2 * (E + i)] : e32[E + i];
  d = min(max(d, 0), N - 1);
  atomicAdd(&deg[d], 1);
}

// ---------- exclusive scan over deg (1024 elems / block) ----------
__global__ void scan_phase1(const int* deg, int n, int* bsums) {
  __shared__ int red[256];
  int tid = threadIdx.x;
  int base = blockIdx.x * 1024 + tid * 4;
  int s = 0;
  for (int k = 0; k < 4; k++) { int i = base + k; if (i < n) s += deg[i]; }
  red[tid] = s; __syncthreads();
  for (int st = 128; st > 0; st >>= 1) {
    if (tid < st) red[tid] += red[tid + st];
    __syncthreads();
  }
  if (tid == 0) bsums[blockIdx.x] = red[0];
}

__global__ void scan_phase2(int* bsums, int nb, int* row_ptr, int n) {
  __shared__ int tmp[1024];
  int tid = threadIdx.x;
  int v = (tid < nb) ? bsums[tid] : 0;
  tmp[tid] = v; __syncthreads();
  for (int st = 1; st < 1024; st <<= 1) {
    int t = (tid >= st) ? tmp[tid - st] : 0;
    __syncthreads();
    tmp[tid] += t;
    __syncthreads();
  }
  if (tid < nb) bsums[tid] = tmp[tid] - v;      // exclusive block offsets
  if (tid == nb - 1) row_ptr[n] = tmp[tid];     // total (= E)
}

__global__ void scan_phase3(const int* deg, int n, const int* boff,
                            int* row_ptr, int* fill, float* invd) {
  __shared__ int red[256];
  int tid = threadIdx.x;
  int base = blockIdx.x * 1024 + tid * 4;
  int d[4]; int s = 0;
  for (int k = 0; k < 4; k++) { int i = base + k; d[k] = (i < n) ? deg[i] : 0; s += d[k]; }
  red[tid] = s; __syncthreads();
  for (int st = 1; st < 256; st <<= 1) {
    int t = (tid >= st) ? red[tid - st] : 0;
    __syncthreads();
    red[tid] += t;
    __syncthreads();
  }
  int run = boff[blockIdx.x] + red[tid] - s;    // exclusive prefix for this thread
  for (int k = 0; k < 4; k++) {
    int i = base + k;
    if (i < n) {
      row_ptr[i] = run; fill[i] = run;
      invd[i] = 1.0f / (float)max(d[k], 1);
      run += d[k];
    }
  }
}

__global__ void fill_csr(const int* e32, int E, int N, const int* flags,
                         int* fill, int* col) {
  int i = blockIdx.x * blockDim.x + threadIdx.x;
  if (i >= E) return;
  int s, d;
  if (flags[0]) { s = e32[2 * i]; d = e32[2 * (E + i)]; }
  else          { s = e32[i];     d = e32[E + i]; }
  s = min(max(s, 0), N - 1);
  d = min(max(d, 0), N - 1);
  int p = atomicAdd(&fill[d], 1);
  col[p] = s;
}

// ---------- pack weights to fp32, lane-coalesced pair layout ----------
__global__ void prep_w(const void* W1l, const void* W1r, const void* b1,
                       const void* W2l, const void* W2r, const void* b2,
                       const int* flags, float4* Wp1f, float2* Wp2f,
                       float* b1f, float* b2f) {
  int tid = threadIdx.x;
  int isf = flags[1];
  auto rd = [&](const void* p, int i) -> float {
    return isf ? ((const float*)p)[i] : bf2f(((const unsigned short*)p)[i]);
  };
  for (int idx = tid; idx < 64 * 64; idx += 256) {
    int p = idx >> 6, j = idx & 63;
    Wp1f[idx] = make_float4(rd(W1l, (2 * p) * HH + j), rd(W1l, (2 * p + 1) * HH + j),
                            rd(W1r, (2 * p) * HH + j), rd(W1r, (2 * p + 1) * HH + j));
  }
  for (int idx = tid; idx < 64 * CC; idx += 256) {
    int p = idx / CC, c = idx % CC;
    int k0 = 2 * p, k1 = 2 * p + 1;
    float a  = (k0 < HH) ? rd(W2l, k0 * CC + c) : rd(W2r, (k0 - HH) * CC + c);
    float bb = (k1 < HH) ? rd(W2l, k1 * CC + c) : rd(W2r, (k1 - HH) * CC + c);
    Wp2f[idx] = make_float2(a, bb);
  }
  if (tid < HH) b1f[tid] = rd(b1, tid);
  if (tid < CC) b2f[tid] = rd(b2, tid);
}

// ---------- transform1: t1 = x@W1_l (bf16), s1 = x@W1_r + b1 (bf16) ----------
__global__ __launch_bounds__(256) void transform1(const void* xraw, const int* flags,
                                                  const float4* Wp1f, const float* b1f,
                                                  unsigned short* t1, unsigned short* s1,
                                                  int N) {
  __shared__ float vx[32 * DD];            // 16 KB: 32 nodes x 128 floats
  int wave = threadIdx.x >> 6, lane = threadIdx.x & 63;
  int nodeBase = blockIdx.x * 32 + wave * 8;
  float* myv = &vx[wave * 8 * DD];

  if (flags[1]) {                                        // fp32 input
    const float2* x2 = (const float2*)xraw;
    for (int k = 0; k < 8; k++) {
      int n = nodeBase + k;
      if (n < N) {
        float2 t = x2[(size_t)n * 64 + lane];
        *(float2*)&myv[k * DD + 2 * lane] = t;
      }
    }
  } else {                                               // bf16 input
    const unsigned int* x32 = (const unsigned int*)xraw;
    for (int k = 0; k < 8; k++) {
      int n = nodeBase + k;
      if (n < N) {
        unsigned int w = x32[(size_t)n * 64 + lane];
        *(float2*)&myv[k * DD + 2 * lane] = make_float2(lo16(w), hi16(w));
      }
    }
  }
  __syncthreads();

  float acct[8] = {0, 0, 0, 0, 0, 0, 0, 0};
  float accs[8] = {0, 0, 0, 0, 0, 0, 0, 0};
  const float2* v2 = (const float2*)myv;
  int j = lane;
  for (int p = 0; p < 64; p++) {
    float4 w = Wp1f[p * 64 + j];
#pragma unroll
    for (int k = 0; k < 8; k++) {
      float2 vv = v2[k * 64 + p];                // broadcast LDS read
      acct[k] += vv.x * w.x + vv.y * w.y;
      accs[k] += vv.x * w.z + vv.y * w.w;
    }
  }
  float bb = b1f[j];
  for (int k = 0; k < 8; k++) {
    int n = nodeBase + k;
    if (n < N) {
      t1[n * HH + j] = f2bf(acct[k]);
      s1[n * HH + j] = f2bf(accs[k] + bb);
    }
  }
}

// ---------- vectorized CSR mean-gather helper ----------
// Wave layout: lane l -> row-group r = l>>3 (8 rows/load), chunk c = l&7 (16B each).
// Accumulates fp32 partials in acc[8]; after call, butterfly-reduce over masks 8/16/32.
__device__ __forceinline__ void gather_rows(const uint4* t8, const int* col,
                                            int start, int end, int r, int c,
                                            float acc[8]) {
  for (int base = start; base < end; base += 16) {
    int i0 = base + r, i1 = base + 8 + r;
    uint4 v0 = make_uint4(0, 0, 0, 0), v1 = make_uint4(0, 0, 0, 0);
    bool g0 = (i0 < end), g1 = (i1 < end);
    int nb0 = g0 ? col[i0] : 0;
    int nb1 = g1 ? col[i1] : 0;
    if (g0) v0 = t8[nb0 * 8 + c];               // 16B = 8 bf16 of row nb0
    if (g1) v1 = t8[nb1 * 8 + c];
    acc[0] += lo16(v0.x) + lo16(v1.x);
    acc[1] += hi16(v0.x) + hi16(v1.x);
    acc[2] += lo16(v0.y) + lo16(v1.y);
    acc[3] += hi16(v0.y) + hi16(v1.y);
    acc[4] += lo16(v0.z) + lo16(v1.z);
    acc[5] += hi16(v0.z) + hi16(v1.z);
    acc[6] += lo16(v0.w) + lo16(v1.w);
    acc[7] += hi16(v0.w) + hi16(v1.w);
  }
#pragma unroll
  for (int m = 8; m <= 32; m <<= 1)
#pragma unroll
    for (int i = 0; i < 8; i++) acc[i] += __shfl_xor(acc[i], m, 64);
}

// ---------- aggregate1: h = relu(mean(t1[nbrs]) + s1) ----------
// one wave per node; 8 neighbor rows per 16B-load
__global__ __launch_bounds__(256) void aggregate1(const unsigned short* t1,
                                                  const unsigned short* s1,
                                                  const int* row_ptr, const float* invd,
                                                  const int* col, unsigned short* h, int N) {
  int wave = threadIdx.x >> 6, lane = threadIdx.x & 63;
  int r = lane >> 3, c = lane & 7;
  int n = blockIdx.x * 4 + wave;
  if (n >= N) return;
  int start = row_ptr[n], end = row_ptr[n + 1];
  float acc[8] = {0, 0, 0, 0, 0, 0, 0, 0};
  gather_rows((const uint4*)t1, col, start, end, r, c, acc);

  if (r == 0) {                                  // lanes 0..7 own features c*8..c*8+7
    float id = invd[n];
    uint4 sv = ((const uint4*)s1)[n * 8 + c];
    float s[8] = {lo16(sv.x), hi16(sv.x), lo16(sv.y), hi16(sv.y),
                  lo16(sv.z), hi16(sv.z), lo16(sv.w), hi16(sv.w)};
    unsigned int o[4];
#pragma unroll
    for (int i = 0; i < 4; i++) {
      float a0 = fmaxf(acc[2 * i] * id + s[2 * i], 0.f);
      float a1 = fmaxf(acc[2 * i + 1] * id + s[2 * i + 1], 0.f);
      o[i] = (unsigned int)f2bf(a0) | ((unsigned int)f2bf(a1) << 16);
    }
    ((uint4*)h)[n * 8 + c] = make_uint4(o[0], o[1], o[2], o[3]);
  }
}

// ---------- layer2 fused: aggh = mean(h[nbrs]); logits = [aggh|h]@W2c + b2; log_softmax ----------
// block=256 (4 waves); each wave owns 4 nodes. Gather vectorized; matvec via LDS stage.
__global__ __launch_bounds__(256) void layer2(const unsigned short* h,
                                              const int* row_ptr, const float* invd,
                                              const int* col, const float2* Wp2f,
                                              const float* b2f,
                                              float* out, int N) {
  __shared__ float v[16 * DD];             // 8 KB: 16 nodes x 128 floats
  int wave = threadIdx.x >> 6, lane = threadIdx.x & 63;
  int r = lane >> 3, c = lane & 7;
  int nodeBase = blockIdx.x * 16 + wave * 4;
  float* myv = &v[wave * 4 * DD];

  for (int k = 0; k < 4; k++) {
    int n = nodeBase + k;
    if (n >= N) continue;
    int start = row_ptr[n], end = row_ptr[n + 1];
    float acc[8] = {0, 0, 0, 0, 0, 0, 0, 0};
    gather_rows((const uint4*)h, col, start, end, r, c, acc);
    if (r == 0) {
      float id = invd[n];
      uint4 sv = ((const uint4*)h)[n * 8 + c];   // self row
      float* dst = &myv[k * DD];
#pragma unroll
      for (int i = 0; i < 8; i++) dst[c * 8 + i] = acc[i] * id;
      dst[64 + c * 8 + 0] = lo16(sv.x); dst[64 + c * 8 + 1] = hi16(sv.x);
      dst[64 + c * 8 + 2] = lo16(sv.y); dst[64 + c * 8 + 3] = hi16(sv.y);
      dst[64 + c * 8 + 4] = lo16(sv.z); dst[64 + c * 8 + 5] = hi16(sv.z);
      dst[64 + c * 8 + 6] = lo16(sv.w); dst[64 + c * 8 + 7] = hi16(sv.w);
    }
  }
  __syncthreads();

  float accc[4] = {0, 0, 0, 0};
  if (lane < CC) {
    const float2* v2 = (const float2*)myv;
    for (int p = 0; p < 64; p++) {
      float2 w = Wp2f[p * CC + lane];
#pragma unroll
      for (int k = 0; k < 4; k++) {
        float2 vv = v2[k * 64 + p];                   // broadcast LDS read
        accc[k] += vv.x * w.x + vv.y * w.y;
      }
    }
    float bb = b2f[lane];
    for (int k = 0; k < 4; k++) accc[k] += bb;
  }

  for (int k = 0; k < 4; k++) {
    int n = nodeBase + k;
    float val = (lane < CC) ? accc[k] : -INFINITY;
    float m = val;
    for (int off = 32; off > 0; off >>= 1) m = fmaxf(m, __shfl_xor(m, off, 64));
    float e = (lane < CC) ? __expf(val - m) : 0.f;
    float ssum = e;
    for (int off = 32; off > 0; off >>= 1) ssum += __shfl_xor(ssum, off, 64);
    if (lane < CC && n < N) {
      out[n * CC + lane] = val - m - __logf(ssum);    // fp32 store
    }
  }
}

extern "C" void kernel_launch(void* const* d_in, const int* in_sizes, int n_in,
                              void* d_out, int out_size, void* d_ws, size_t ws_size,
                              hipStream_t stream) {
  const void* x   = d_in[0];
  const int*  e   = (const int*)d_in[1];
  const void* W1l = d_in[2];
  const void* W1r = d_in[3];
  const void* b1  = d_in[4];
  const void* W2l = d_in[5];
  const void* W2r = d_in[6];
  const void* b2  = d_in[7];
  float* out = (float*)d_out;

  const int N = in_sizes[0] / DD;       // 100000
  const int E = in_sizes[1] / 2;        // 1600000
  const int NB = (N + 1023) / 1024;     // scan blocks (98)

  char* w = (char*)d_ws;
  size_t off = 0;
  auto carve = [&](size_t bytes) -> void* {
    void* p = (void*)(w + off);
    off += (bytes + 255) & ~(size_t)255;
    return p;
  };
  int* col     = (int*)carve((size_t)E * 4);
  int* deg     = (int*)carve((size_t)N * 4);
  int* row_ptr = (int*)carve((size_t)(N + 1) * 4);
  int* fill    = (int*)carve((size_t)N * 4);
  float* invd  = (float*)carve((size_t)N * 4);
  int* bsums   = (int*)carve((size_t)NB * 4);
  int* flags   = (int*)carve(8);
  unsigned short* t1  = (unsigned short*)carve((size_t)N * HH * 2);
  unsigned short* s1  = (unsigned short*)carve((size_t)N * HH * 2);
  unsigned short* h   = (unsigned short*)carve((size_t)N * HH * 2);
  float4* Wp1f = (float4*)carve(64 * 64 * sizeof(float4));
  float2* Wp2f = (float2*)carve(64 * CC * sizeof(float2));
  float* b1f   = (float*)carve(HH * sizeof(float));
  float* b2f   = (float*)carve(CC * sizeof(float));
  (void)ws_size; (void)n_in; (void)out_size;

  hipMemsetAsync(deg, 0, (size_t)N * 4, stream);
  detect<<<1, 256, 0, stream>>>((const unsigned int*)e, (const unsigned int*)x, flags);
  count_deg<<<(E + 255) / 256, 256, 0, stream>>>(e, E, N, flags, deg);
  scan_phase1<<<NB, 256, 0, stream>>>(deg, N, bsums);
  scan_phase2<<<1, 1024, 0, stream>>>(bsums, NB, row_ptr, N);
  scan_phase3<<<NB, 256, 0, stream>>>(deg, N, bsums, row_ptr, fill, invd);
  fill_csr<<<(E + 255) / 256, 256, 0, stream>>>(e, E, N, flags, fill, col);
  prep_w<<<1, 256, 0, stream>>>(W1l, W1r, b1, W2l, W2r, b2, flags, Wp1f, Wp2f, b1f, b2f);
  transform1<<<(N + 31) / 32, 256, 0, stream>>>(x, flags, Wp1f, b1f, t1, s1, N);
  aggregate1<<<(N + 3) / 4, 256, 0, stream>>>(t1, s1, row_ptr, invd, col, h, N);
  layer2<<<(N + 15) / 16, 256, 0, stream>>>(h, row_ptr, invd, col, Wp2f, b2f, out, N);
}